// Round 15
// baseline (134.849 us; speedup 1.0000x reference)
//
#include <hip/hip_runtime.h>
#include <math.h>

#define NE 64
#define NTASK 6
#define BLK 256
#define GRID 2048

// ---------------------------------------------------------------------------
// Kernel A: per-task precompute (6 x 64 tables) in f64 internally, f32 out.
// Outputs plain layout: clg[t*64+e], nsg[t*64+e]. Also zeroes `load`.
// ---------------------------------------------------------------------------
__global__ void precompute_kernel(
    const float* __restrict__ embed_table,   // (6,32)
    const float* __restrict__ expert_keys,   // (32,32)
    const float* __restrict__ in_proj_w,     // (96,32)
    const float* __restrict__ in_proj_b,     // (96,)
    const float* __restrict__ fc_gate_w,     // (64,32)
    const float* __restrict__ fc_gate_b,     // (64,)
    const float* __restrict__ fc_noise_w,    // (64,32)
    const float* __restrict__ fc_noise_b,    // (64,)
    float* __restrict__ clg,                 // 384 floats [t*64+e]
    float* __restrict__ nsg,                 // 384 floats [t*64+e]
    float* __restrict__ load)                // (64,) zero-init
{
    __shared__ float s_win[96 * 32];
    __shared__ float s_wg[64 * 32];
    __shared__ float s_wn[64 * 32];
    __shared__ float s_keys[32 * 32];
    __shared__ float s_emb[6 * 32];
    __shared__ float s_bin[96], s_bg[64], s_bn[64];
    __shared__ double Ksh[32][32];
    __shared__ double Qsh[6][32];
    __shared__ double sc[24][32];
    __shared__ double attn[6][32];
    __shared__ double ew[6][32];
    __shared__ double red[24];
    __shared__ double red2[6];
    const int tid = threadIdx.x;

    if (tid < NE) load[tid] = 0.f;

    for (int i = tid; i < 96 * 32; i += BLK) s_win[i] = in_proj_w[i];
    for (int i = tid; i < 64 * 32; i += BLK) { s_wg[i] = fc_gate_w[i]; s_wn[i] = fc_noise_w[i]; }
    for (int i = tid; i < 32 * 32; i += BLK) s_keys[i] = expert_keys[i];
    for (int i = tid; i < 6 * 32;  i += BLK) s_emb[i] = embed_table[i];
    if (tid < 96) s_bin[tid] = in_proj_b[tid];
    if (tid < 64) { s_bg[tid] = fc_gate_b[tid]; s_bn[tid] = fc_noise_b[tid]; }
    __syncthreads();

    for (int idx = tid; idx < 32 * 32; idx += BLK) {
        int s = idx >> 5, j = idx & 31;
        double acc = (double)s_bin[32 + j];
        for (int d = 0; d < 32; ++d)
            acc += (double)s_keys[s * 32 + d] * (double)s_win[(32 + j) * 32 + d];
        Ksh[s][j] = acc;
    }
    for (int idx = tid; idx < NTASK * 32; idx += BLK) {
        int t = idx >> 5, j = idx & 31;
        double acc = (double)s_bin[j];
        for (int d = 0; d < 32; ++d)
            acc += (double)s_emb[t * 32 + d] * (double)s_win[j * 32 + d];
        Qsh[t][j] = acc;
    }
    __syncthreads();

    const double SCALE = 1.0 / (double)((float)2.8284271247461903);
    for (int idx = tid; idx < 24 * 32; idx += BLK) {
        int th = idx >> 5, s = idx & 31;
        int t = th >> 2, h = th & 3;
        double acc = 0.0;
        for (int d = 0; d < 8; ++d)
            acc += Qsh[t][h * 8 + d] * Ksh[s][h * 8 + d];
        sc[th][s] = acc * SCALE;
    }
    __syncthreads();
    if (tid < 24) {
        double m = sc[tid][0];
        for (int s = 1; s < 32; ++s) m = fmax(m, sc[tid][s]);
        red[tid] = m;
    }
    __syncthreads();
    for (int idx = tid; idx < 24 * 32; idx += BLK) {
        int th = idx >> 5, s = idx & 31;
        sc[th][s] = exp(sc[th][s] - red[th]);
    }
    __syncthreads();
    if (tid < 24) {
        double sum = 0.0;
        for (int s = 0; s < 32; ++s) sum += sc[tid][s];
        red[tid] = 1.0 / sum;
    }
    __syncthreads();
    for (int idx = tid; idx < NTASK * 32; idx += BLK) {
        int t = idx >> 5, s = idx & 31;
        attn[t][s] = 0.25 * (sc[t*4+0][s]*red[t*4+0] + sc[t*4+1][s]*red[t*4+1]
                           + sc[t*4+2][s]*red[t*4+2] + sc[t*4+3][s]*red[t*4+3]);
    }
    __syncthreads();
    if (tid < NTASK) {
        double m = attn[tid][0];
        for (int s = 1; s < 32; ++s) m = fmax(m, attn[tid][s]);
        red2[tid] = m;
    }
    __syncthreads();
    for (int idx = tid; idx < NTASK * 32; idx += BLK) {
        int t = idx >> 5, s = idx & 31;
        ew[t][s] = exp(attn[t][s] - red2[t]);
    }
    __syncthreads();
    if (tid < NTASK) {
        double sum = 0.0;
        for (int s = 0; s < 32; ++s) sum += ew[tid][s];
        red2[tid] = 1.0 / sum;
    }
    __syncthreads();

    for (int idx = tid; idx < NTASK * NE; idx += BLK) {
        int t = idx >> 6, e = idx & 63;
        double inv = red2[t];
        double a  = (double)s_bg[e];
        double n0 = (double)s_bn[e];
        for (int d = 0; d < 32; ++d) {
            double w = ew[t][d] * inv;
            a  += w * (double)s_wg[e * 32 + d];
            n0 += w * (double)s_wn[e * 32 + d];
        }
        double sp = (n0 > 0.0) ? (n0 + log1p(exp(-n0))) : log1p(exp(n0));
        clg[idx] = (float)a;
        nsg[idx] = (float)(sp + 0.01);
    }
}

// ---------------------------------------------------------------------------
// Kernel B: 16 lanes per row (4 experts per lane), 4 rows per wave-iteration.
// A wave's contiguous 1KB load gives each lane exactly its own experts'
// noise -- no LDS bounce. Top-2: in-lane cascade of 4 + 4 butterfly rounds
// (each shfl serves 4 rows). All 16 lanes of a row end with the winners, so
// the store is 12 selects + the same contiguous 1KB store. No f64.
// ---------------------------------------------------------------------------
__global__ __launch_bounds__(BLK) void router_kernel(
    const int*    __restrict__ taskID,
    const float4* __restrict__ noise4,   // (B*16)
    const float4* __restrict__ clg4,     // 96 float4  [t*16+sl]
    const float4* __restrict__ nsg4,     // 96 float4
    float4* __restrict__ gates4,         // (B*16)
    float*  __restrict__ load,           // (64,)
    int B)
{
    __shared__ float4 s_cl[96], s_ns[96];   // 3 KB
    __shared__ float  s_load[NE];

    const int tid = threadIdx.x;
    if (tid < 96) { s_cl[tid] = clg4[tid]; s_ns[tid] = nsg4[tid]; }
    if (tid < NE) s_load[tid] = 0.f;
    __syncthreads();

    const int lane = tid & 63;
    const int sl   = lane & 15;     // segment (4 experts) within row
    const int rsub = lane >> 4;     // row within 4-row group
    const int e0   = sl * 4;
    const int W = (blockIdx.x * BLK + tid) >> 6;
    const int nWaves = GRID * (BLK / 64);
    const int nG = (B + 3) >> 2;    // 4 rows per group
    const int n4 = B * 16;
    const float4 zero4 = make_float4(0.f, 0.f, 0.f, 0.f);

    float4 cur = zero4;
    int tcur = 0, rowc = 0;
    if (W < nG) {
        const int idx = W * 64 + lane;
        cur = (idx < n4) ? noise4[idx] : zero4;
        rowc = W * 4 + rsub;
        tcur = (rowc < B) ? taskID[rowc] : 0;
    }

    for (int g = W; g < nG; g += nWaves) {
        // ---- prefetch next group (1 contiguous load + taskID) ----
        const int gn = g + nWaves;
        float4 nxt = zero4; int tnxt = 0, rown = 0;
        if (gn < nG) {
            const int idx = gn * 64 + lane;
            nxt = (idx < n4) ? noise4[idx] : zero4;
            rown = gn * 4 + rsub;
            tnxt = (rown < B) ? taskID[rown] : 0;
        }

        // ---- logits for this lane's 4 experts (np rounding: mul then add) ----
        const float4 c4 = s_cl[tcur * 16 + sl];
        const float4 s4 = s_ns[tcur * 16 + sl];
        const float l0 = __fadd_rn(c4.x, __fmul_rn(cur.x, s4.x));
        const float l1 = __fadd_rn(c4.y, __fmul_rn(cur.y, s4.y));
        const float l2 = __fadd_rn(c4.z, __fmul_rn(cur.z, s4.z));
        const float l3 = __fadd_rn(c4.w, __fmul_rn(cur.w, s4.w));

        // ---- in-lane top-2 of 4 (ascending index, strict >) ----
        float v1 = -INFINITY, v2 = -INFINITY;
        int   i1 = 0, i2 = 0;
#define INS2(l_, e_) {                                                         \
        const bool b1_ = (l_) > v1, b2_ = (l_) > v2;                           \
        v2 = b1_ ? v1 : (b2_ ? (l_) : v2);                                     \
        i2 = b1_ ? i1 : (b2_ ? (e_) : i2);                                     \
        v1 = b1_ ? (l_) : v1;                                                  \
        i1 = b1_ ? (e_) : i1; }
        INS2(l0, e0 + 0); INS2(l1, e0 + 1); INS2(l2, e0 + 2); INS2(l3, e0 + 3);
#undef INS2

        // ---- merge across the 16 lanes of the row (4 butterfly rounds) ----
        #pragma unroll
        for (int m = 1; m <= 8; m <<= 1) {
            const float w1 = __shfl_xor(v1, m), w2 = __shfl_xor(v2, m);
            const int   j1 = __shfl_xor(i1, m), j2 = __shfl_xor(i2, m);
            const bool aw = (v1 > w1) || (v1 == w1 && i1 < j1);
            const float p1 = aw ? v1 : w1, p2 = aw ? v2 : w2;
            const int   pi1 = aw ? i1 : j1, pi2 = aw ? i2 : j2;
            const float u1 = aw ? w1 : v1;
            const int   ui1 = aw ? j1 : i1;
            const bool b2 = (p2 > u1) || (p2 == u1 && pi2 < ui1);
            v1 = p1;  i1 = pi1;
            v2 = b2 ? p2 : u1;  i2 = b2 ? pi2 : ui1;
        }

        // ---- 2-way softmax (f32; selection fixed) ----
        const float e2x = expf(v2 - v1);
        const float g1 = 1.0f / (1.0f + e2x);
        const float g2 = e2x / (1.0f + e2x);

        if (sl == 0 && rowc < B) {
            atomicAdd(&s_load[i1], g1);
            atomicAdd(&s_load[i2], g2);
        }

        // ---- contiguous store: this lane's float4 of the gates row ----
        float4 w;
        w.x = (e0 + 0 == i1) ? g1 : ((e0 + 0 == i2) ? g2 : 0.f);
        w.y = (e0 + 1 == i1) ? g1 : ((e0 + 1 == i2) ? g2 : 0.f);
        w.z = (e0 + 2 == i1) ? g1 : ((e0 + 2 == i2) ? g2 : 0.f);
        w.w = (e0 + 3 == i1) ? g1 : ((e0 + 3 == i2) ? g2 : 0.f);
        const int sidx = g * 64 + lane;
        if (sidx < n4) gates4[sidx] = w;

        // ---- rotate ----
        cur = nxt; tcur = tnxt; rowc = rown;
    }
    __syncthreads();
    if (tid < NE) atomicAdd(&load[tid], s_load[tid]);
}

// ---------------------------------------------------------------------------
extern "C" void kernel_launch(void* const* d_in, const int* in_sizes, int n_in,
                              void* d_out, int out_size, void* d_ws, size_t ws_size,
                              hipStream_t stream) {
    const int*   taskID      = (const int*)  d_in[0];
    const float* embed_table = (const float*)d_in[1];
    const float* expert_keys = (const float*)d_in[2];
    const float* in_proj_w   = (const float*)d_in[3];
    const float* in_proj_b   = (const float*)d_in[4];
    const float* fc_gate_w   = (const float*)d_in[5];
    const float* fc_gate_b   = (const float*)d_in[6];
    const float* fc_noise_w  = (const float*)d_in[7];
    const float* fc_noise_b  = (const float*)d_in[8];
    const float* noise       = (const float*)d_in[9];

    const int B = in_sizes[0];

    float* clg = (float*)d_ws;         // 384 floats
    float* nsg = clg + 384;            // 384 floats

    float* gates = (float*)d_out;
    float* load  = gates + (size_t)B * NE;

    precompute_kernel<<<1, BLK, 0, stream>>>(embed_table, expert_keys, in_proj_w, in_proj_b,
                                             fc_gate_w, fc_gate_b, fc_noise_w, fc_noise_b,
                                             clg, nsg, load);

    router_kernel<<<GRID, BLK, 0, stream>>>(taskID, (const float4*)noise,
                                            (const float4*)clg, (const float4*)nsg,
                                            (float4*)gates, load, B);
}